// Round 7
// baseline (28392.355 us; speedup 1.0000x reference)
//
#include <hip/hip_runtime.h>

#define H 64
#define G4 256  // 4*H
#define CH 64   // pipeline chunk (timesteps per flag handoff)

__device__ __forceinline__ float sigmoid_f(float x) {
  return 1.f / (1.f + __expf(-x));
}
__device__ __forceinline__ float tanh_f(float x) {
  float e = __expf(2.f * x);
  return 1.f - 2.f / (e + 1.f);
}
// Broadcast lane `lane`'s value (lane uniform) via v_readlane -> SGPR.
__device__ __forceinline__ float rdlane(float v, int lane) {
  return __int_as_float(__builtin_amdgcn_readlane(__float_as_int(v), lane));
}
// Workgroup barrier draining ONLY lgkmcnt (LDS); globals stay in flight.
__device__ __forceinline__ void wg_barrier() {
  asm volatile("s_waitcnt lgkmcnt(0)\n\ts_barrier" ::: "memory");
}

// 3-block systolic pipeline, one LSTM layer per block (per CU).
// 512 threads = 8 waves; wave = (half,gate): g=w&3, half=w>>2 picks k-range
// [32*half, 32*half+32). Lane l = hidden unit. Thread (half,g,l) holds
// U[k][g*64+l] (+ W[k][g*64+l] for roles 1,2) for its 32 k's -> 64 weight
// VGPRs (fits RA budget). h lives in LANES; h[k] broadcast via v_readlane
// (no LDS in the dot). Partials exchanged via parity-double-buffered LDS,
// ONE lgkm-barrier per step. Cell update computed redundantly by all waves.
// Inter-layer h handoff: RELAXED AGENT-SCOPE ATOMICS (coherent across XCD
// L2s) + release/acquire chunk flags. Cooperative launch => co-residency.
__global__ __attribute__((amdgpu_flat_work_group_size(512, 512),
                          amdgpu_waves_per_eu(2, 2)))
void scan_pipe(const float* __restrict__ x,
               const float* __restrict__ W1, const float* __restrict__ U1,
               const float* __restrict__ b1,
               const float* __restrict__ W2, const float* __restrict__ U2,
               const float* __restrict__ b2,
               const float* __restrict__ W3, const float* __restrict__ U3,
               const float* __restrict__ b3,
               float* __restrict__ h1seq, float* __restrict__ h2seq,
               float* __restrict__ h3last, int* __restrict__ flags, int T) {
  const int role = (int)blockIdx.x;  // 0,1,2 = layer
  const int tid = (int)threadIdx.x;
  const int l = tid & 63;
  const int w = tid >> 6;
  const int g = w & 3;
  const int half = w >> 2;
  const int j = (g << 6) | l;
  const int kbase = half << 5;

  const float* U  = (role == 0) ? U1 : ((role == 1) ? U2 : U3);
  const float* Wp = (role == 0) ? U1 : ((role == 1) ? W2 : W3);  // dummy for 0
  const float* bb = (role == 0) ? b1 : ((role == 1) ? b2 : b3);

  float uw[32];
#pragma unroll
  for (int k = 0; k < 32; ++k) uw[k] = U[(kbase + k) * G4 + j];
  float pw[32];
#pragma unroll
  for (int k = 0; k < 32; ++k) pw[k] = Wp[(kbase + k) * G4 + j];
#pragma unroll
  for (int k = 0; k < 32; ++k) asm volatile("" : "+v"(uw[k]));
#pragma unroll
  for (int k = 0; k < 32; ++k) asm volatile("" : "+v"(pw[k]));

  float w1a = 0.f, w1b = 0.f;
  if (role == 0 && half == 0) { w1a = W1[j]; w1b = W1[G4 + j]; }
  const float bj = (half == 0) ? bb[j] : 0.f;  // bias counted once (half 0)

  const float* hin = (role == 1) ? h1seq : h2seq;
  float* hout = (role == 0) ? h1seq : h2seq;
  int* flag_self = flags + role;
  int* flag_prev = flags + (role > 0 ? role - 1 : 0);

  __shared__ float shp[2][8 * H];  // parity-double-buffered partials

  float c = 0.f, hreg = 0.f;
  float x0c = 0.f, x1c = 0.f;
  if (role == 0 && half == 0) { x0c = x[0]; x1c = x[1]; }

  for (int t0 = 0; t0 < T; t0 += CH) {
    if (role > 0) {
      if (tid < 64) {  // wave 0 polls; others wait at the barrier
        const int need = t0 + CH;
        while (__hip_atomic_load(flag_prev, __ATOMIC_ACQUIRE,
                                 __HIP_MEMORY_SCOPE_AGENT) < need) {
          __builtin_amdgcn_s_sleep(8);
        }
      }
      __syncthreads();
    }
    // h_prev prefetch pipeline: 1 coherent scalar load/thread/step,
    // consumed next step (latency hidden); chunk-start load stalls once.
    float hpl = 0.f, hpn = 0.f;
    if (role > 0)
      hpl = __hip_atomic_load(&hin[(size_t)t0 * H + l], __ATOMIC_RELAXED,
                              __HIP_MEMORY_SCOPE_AGENT);

    for (int tt = 0; tt < CH; ++tt) {
      const int t = t0 + tt;
      float xw0;
      if (role == 0) {
        // x-projection ONLY in half 0 (half 1 would double-count it:
        // z = P[half0] + P[half1] — this was round 6's correctness bug).
        xw0 = (half == 0) ? fmaf(x0c, w1a, fmaf(x1c, w1b, bj)) : 0.f;
        if (half == 0) {
          const int tn = (t + 1 < T) ? (t + 1) : t;
          x0c = x[2 * tn]; x1c = x[2 * tn + 1];  // prefetch next x
        }
      } else {
        xw0 = bj;
        if (tt + 1 < CH)
          hpn = __hip_atomic_load(&hin[(size_t)(t + 1) * H + l],
                                  __ATOMIC_RELAXED, __HIP_MEMORY_SCOPE_AGENT);
      }

      float a0 = xw0, a1 = 0.f, a2 = 0.f, a3 = 0.f;
#pragma unroll
      for (int k = 0; k < 32; k += 4) {
        a0 = fmaf(rdlane(hreg, kbase + k),     uw[k],     a0);
        a1 = fmaf(rdlane(hreg, kbase + k + 1), uw[k + 1], a1);
        a2 = fmaf(rdlane(hreg, kbase + k + 2), uw[k + 2], a2);
        a3 = fmaf(rdlane(hreg, kbase + k + 3), uw[k + 3], a3);
      }
      if (role > 0) {
#pragma unroll
        for (int k = 0; k < 32; k += 4) {
          a0 = fmaf(rdlane(hpl, kbase + k),     pw[k],     a0);
          a1 = fmaf(rdlane(hpl, kbase + k + 1), pw[k + 1], a1);
          a2 = fmaf(rdlane(hpl, kbase + k + 2), pw[k + 2], a2);
          a3 = fmaf(rdlane(hpl, kbase + k + 3), pw[k + 3], a3);
        }
      }
      const int par = t & 1;
      shp[par][(w << 6) | l] = (a0 + a1) + (a2 + a3);  // stride-1: no conflict
      wg_barrier();
      // Parity safety with ONE barrier/step: a thread reaches the same-parity
      // write of step t+2 only after step t+1's barrier, which it can pass
      // only after its own step-t reads completed (lgkmcnt(0) pre-barrier).
      const float* P = &shp[par][0];
      const float z0 = P[(0 << 6) | l] + P[(4 << 6) | l];
      const float z1 = P[(1 << 6) | l] + P[(5 << 6) | l];
      const float z2 = P[(2 << 6) | l] + P[(6 << 6) | l];
      const float z3 = P[(3 << 6) | l] + P[(7 << 6) | l];
      const float gi = sigmoid_f(z0);
      const float gf = sigmoid_f(z1);
      const float gc = tanh_f(z2);
      const float go = sigmoid_f(z3);
      c = fmaf(gf, c, gi * gc);
      hreg = go * tanh_f(c);  // redundantly computed by all 8 waves

      if (role < 2) {
        if (tid < H)  // coherent fire-and-forget store (drained at chunk end)
          __hip_atomic_store(&hout[(size_t)t * H + l], hreg, __ATOMIC_RELAXED,
                             __HIP_MEMORY_SCOPE_AGENT);
      } else if (t == T - 1) {
        if (tid < H) h3last[l] = hreg;  // cross-kernel visibility is implicit
      }
      hpl = hpn;
    }
    if (role < 2) {
      __syncthreads();  // vmcnt(0): all waves' h stores are at coherent point
      if (tid == 0)
        __hip_atomic_store(flag_self, t0 + CH, __ATOMIC_RELEASE,
                           __HIP_MEMORY_SCOPE_AGENT);
    }
  }
}

// Dense head: relu(h3@Wd1+bd1) -> relu(@Wd2+bd2) -> @Wl+bl
__global__ __launch_bounds__(64) void head_k(const float* __restrict__ hlast,
                                             const float* __restrict__ Wd1,
                                             const float* __restrict__ bd1,
                                             const float* __restrict__ Wd2,
                                             const float* __restrict__ bd2,
                                             const float* __restrict__ Wl,
                                             const float* __restrict__ bl,
                                             float* __restrict__ out) {
  __shared__ float s_h[H];
  __shared__ float s_a[20];
  __shared__ float s_b[20];
  const int j = threadIdx.x;
  s_h[j] = hlast[j];
  __syncthreads();
  if (j < 20) {
    float acc = bd1[j];
#pragma unroll
    for (int k = 0; k < H; ++k) acc = fmaf(s_h[k], Wd1[k * 20 + j], acc);
    s_a[j] = fmaxf(acc, 0.f);
  }
  __syncthreads();
  if (j < 20) {
    float acc = bd2[j];
#pragma unroll
    for (int k = 0; k < 20; ++k) acc = fmaf(s_a[k], Wd2[k * 20 + j], acc);
    s_b[j] = fmaxf(acc, 0.f);
  }
  __syncthreads();
  if (j < 10) {
    float acc = bl[j];
#pragma unroll
    for (int k = 0; k < 20; ++k) acc = fmaf(s_b[k], Wl[k * 10 + j], acc);
    out[j] = acc;
  }
}

extern "C" void kernel_launch(void* const* d_in, const int* in_sizes, int n_in,
                              void* d_out, int out_size, void* d_ws, size_t ws_size,
                              hipStream_t stream) {
  const float* x   = (const float*)d_in[0];
  const float* W1  = (const float*)d_in[1];
  const float* U1  = (const float*)d_in[2];
  const float* b1  = (const float*)d_in[3];
  const float* W2  = (const float*)d_in[4];
  const float* U2  = (const float*)d_in[5];
  const float* b2  = (const float*)d_in[6];
  const float* W3  = (const float*)d_in[7];
  const float* U3  = (const float*)d_in[8];
  const float* b3  = (const float*)d_in[9];
  const float* Wd1 = (const float*)d_in[10];
  const float* bd1 = (const float*)d_in[11];
  const float* Wd2 = (const float*)d_in[12];
  const float* bd2 = (const float*)d_in[13];
  const float* Wl  = (const float*)d_in[14];
  const float* bl  = (const float*)d_in[15];
  int T = in_sizes[0] / 2;  // 16384

  // workspace: h1seq [T,64] | h2seq [T,64] | h3last [64] | flags[4]
  float* h1seq = (float*)d_ws;
  float* h2seq = h1seq + (size_t)T * H;
  float* h3last = h2seq + (size_t)T * H;
  int* flags = (int*)(h3last + H);

  hipMemsetAsync(flags, 0, 4 * sizeof(int), stream);

  void* args[] = {(void*)&x,  (void*)&W1, (void*)&U1, (void*)&b1,
                  (void*)&W2, (void*)&U2, (void*)&b2, (void*)&W3,
                  (void*)&U3, (void*)&b3, (void*)&h1seq, (void*)&h2seq,
                  (void*)&h3last, (void*)&flags, (void*)&T};
  // Cooperative launch: the 3 layer-blocks are guaranteed co-resident.
  hipLaunchCooperativeKernel((const void*)scan_pipe, dim3(3), dim3(512), args,
                             0, stream);

  head_k<<<1, 64, 0, stream>>>(h3last, Wd1, bd1, Wd2, bd2, Wl, bl,
                               (float*)d_out);
}

// Round 9
// 18822.806 us; speedup vs baseline: 1.5084x; 1.5084x over previous
//
#include <hip/hip_runtime.h>

#define H 64
#define G4 256  // 4*H

// __builtin_amdgcn_cvt_pkrtz returns a __fp16 vector; __builtin_amdgcn_fdot2
// takes _Float16 vectors. Keep both typedefs and pun through int.
typedef _Float16 f16x2 __attribute__((ext_vector_type(2)));
typedef __fp16 p16x2 __attribute__((ext_vector_type(2)));

__device__ __forceinline__ float sigmoid_f(float x) {
  return 1.f / (1.f + __expf(-x));
}
__device__ __forceinline__ float tanh_f(float x) {
  float e = __expf(2.f * x);
  return 1.f - 2.f / (e + 1.f);
}
__device__ __forceinline__ f16x2 as_h2(int v) {
  union { int i; f16x2 h; } u; u.i = v; return u.h;
}
__device__ __forceinline__ int pack_f16(float lo, float hi) {
  union { p16x2 h; int i; } u;
  u.h = __builtin_amdgcn_cvt_pkrtz(lo, hi);
  return u.i;
}
// Workgroup barrier draining ONLY lgkmcnt (LDS); globals stay in flight.
__device__ __forceinline__ void wg_barrier() {
  asm volatile("s_waitcnt lgkmcnt(0)\n\ts_barrier" ::: "memory");
}

// xw[t][j] = x[t][0]*W[0][j] + x[t][1]*W[1][j] + b[j]   (f32)
__global__ __launch_bounds__(G4) void proj_x(const float* __restrict__ x,
                                             const float* __restrict__ W,
                                             const float* __restrict__ b,
                                             float* __restrict__ xw) {
  const int t = blockIdx.x;
  const int j = threadIdx.x;
  xw[(size_t)t * G4 + j] =
      fmaf(x[2 * t], W[j], fmaf(x[2 * t + 1], W[G4 + j], b[j]));
}

// Fused 3-layer systolic LSTM scan, ONE block, 768 threads = 3 layers x 4
// waves. Thread (L, g, l): layer L, gate g (wave-in-layer), unit l (lane).
// Layer L processes t = s - L at global step s.
//
// Per step, per thread:
//   phase D: z[g*64+l] = base + dot_f16(h_own) [+ dot_f16(h_prev)], activate,
//            write sh_a.  h_own is broadcast from the thread's OWN wave via
//            v_readlane of packed f16 pairs (redundant cell => every wave's
//            lane l holds h[l]); h_prev comes as 32 packed pairs via one LDS
//            read + readlane. 32 rdlane + 32 fdot2 per matrix.
//   phase C: read 4 gates from sh_a, redundant cell update (c[l] tracked by
//            all 4 waves of the layer), pack h into f16 pair; layers 0,1
//            wave g=0 publish pairs to LDS for the next layer.
// Sync: two lgkm-only barriers/step. Write->read audit (sh_a: W preB1/R
// postB1 guarded by B1, R postB1/W next-preB1 guarded by B2; sh_hp: W
// postB1/R next-preB1 guarded by B2, R preB1/W postB1 guarded by B1) =>
// no parity buffers needed.
// Weights: f16-packed, 32 VGPR (U) + 32 (W) -- inside the proven ~88-VGPR
// regime (f32's 128/thread was refused by RA in rounds 3-5).
__global__ __attribute__((amdgpu_flat_work_group_size(768, 768),
                          amdgpu_waves_per_eu(3, 3)))
void fused_scan(const float* __restrict__ xw,  // [T,256] = x@W1+b1 (f32)
                const float* __restrict__ U1,
                const float* __restrict__ W2, const float* __restrict__ U2,
                const float* __restrict__ b2,
                const float* __restrict__ W3, const float* __restrict__ U3,
                const float* __restrict__ b3,
                float* __restrict__ h3out, int T) {
  __shared__ float sh_a[3 * G4];  // gate activations per layer
  __shared__ int sh_hp[2 * 32];   // packed f16 h pairs, layers 0,1 -> next

  const int tid = (int)threadIdx.x;
  const int L = tid >> 8;     // layer (wave-uniform)
  const int j = tid & 255;    // gate column within layer
  const int g = j >> 6;       // gate index: 0=i,1=f,2=g(tanh),3=o (wave-unif)
  const int l = j & 63;       // hidden unit = lane

  const float* U  = (L == 0) ? U1 : ((L == 1) ? U2 : U3);
  const float* Wp = (L == 0) ? U1 : ((L == 1) ? W2 : W3);  // dummy for L0

  // f16-packed weight columns: upk[k] = (U[2k][j], U[2k+1][j])
  int upk[32], wpk[32];
#pragma unroll
  for (int k = 0; k < 32; ++k)
    upk[k] = pack_f16(U[(2 * k) * G4 + j], U[(2 * k + 1) * G4 + j]);
#pragma unroll
  for (int k = 0; k < 32; ++k)
    wpk[k] = pack_f16(Wp[(2 * k) * G4 + j], Wp[(2 * k + 1) * G4 + j]);
#pragma unroll
  for (int k = 0; k < 32; ++k) asm volatile("" : "+v"(upk[k]));
#pragma unroll
  for (int k = 0; k < 32; ++k) asm volatile("" : "+v"(wpk[k]));

  float bj = 0.f;
  if (L == 1) bj = b2[j];
  if (L == 2) bj = b3[j];

  float c = 0.f;
  int hpk = 0;  // own-layer h, packed f16 pair (lane 2k holds (h[2k],h[2k+1]))
  if (tid < 64) { sh_hp[tid] = 0; }
  wg_barrier();

  float nxt = 0.f;
  if (L == 0) nxt = xw[j];  // 1-step-ahead xw prefetch

  const int S = T + 2;
  for (int s = 0; s < S; ++s) {
    const int t = s - L;
    const bool active = (t >= 0) && (t < T);  // uniform within layer

    // ---- phase D: dot + activation ----
    if (active) {
      float z0, z1 = 0.f;
      int hp = 0;
      if (L == 0) {
        z0 = nxt;
        const int sn = (s + 1 < T) ? (s + 1) : (T - 1);
        nxt = xw[(size_t)sn * G4 + j];  // fire-and-forget prefetch
      } else {
        z0 = bj;
        hp = sh_hp[(L - 1) * 32 + (l & 31)];  // lane k<32 holds pair k
      }
#pragma unroll
      for (int k = 0; k < 32; k += 2) {
        z0 = __builtin_amdgcn_fdot2(
            as_h2(__builtin_amdgcn_readlane(hpk, 2 * k)), as_h2(upk[k]), z0,
            false);
        z1 = __builtin_amdgcn_fdot2(
            as_h2(__builtin_amdgcn_readlane(hpk, 2 * k + 2)), as_h2(upk[k + 1]),
            z1, false);
      }
      if (L > 0) {
        float z2 = 0.f, z3 = 0.f;
#pragma unroll
        for (int k = 0; k < 32; k += 2) {
          z2 = __builtin_amdgcn_fdot2(
              as_h2(__builtin_amdgcn_readlane(hp, k)), as_h2(wpk[k]), z2,
              false);
          z3 = __builtin_amdgcn_fdot2(
              as_h2(__builtin_amdgcn_readlane(hp, k + 1)), as_h2(wpk[k + 1]),
              z3, false);
        }
        z0 += z2 + z3;
      }
      const float z = z0 + z1;
      sh_a[(L << 8) + j] = (g == 2) ? tanh_f(z) : sigmoid_f(z);
    }
    wg_barrier();  // B1

    // ---- phase C: redundant cell update ----
    if (active) {
      const int base = (L << 8) + l;
      const float gi = sh_a[base];
      const float gf = sh_a[base + 64];
      const float gg = sh_a[base + 128];
      const float go = sh_a[base + 192];
      c = fmaf(gf, c, gi * gg);
      const float h = go * tanh_f(c);
      const float hx = __shfl_xor(h, 1, 64);
      hpk = pack_f16(h, hx);  // even lanes: (h[2k], h[2k+1]) in order
      if (L < 2) {
        if (g == 0 && (l & 1) == 0) sh_hp[(L << 5) + (l >> 1)] = hpk;
      } else if (t == T - 1) {
        if (g == 0) h3out[l] = h;  // f32 result for the head
      }
    }
    wg_barrier();  // B2
  }
}

// Dense head: relu(h3@Wd1+bd1) -> relu(@Wd2+bd2) -> @Wl+bl  (all f32)
__global__ __launch_bounds__(64) void head_k(const float* __restrict__ hlast,
                                             const float* __restrict__ Wd1,
                                             const float* __restrict__ bd1,
                                             const float* __restrict__ Wd2,
                                             const float* __restrict__ bd2,
                                             const float* __restrict__ Wl,
                                             const float* __restrict__ bl,
                                             float* __restrict__ out) {
  __shared__ float s_h[H];
  __shared__ float s_a[20];
  __shared__ float s_b[20];
  const int j = threadIdx.x;
  s_h[j] = hlast[j];
  __syncthreads();
  if (j < 20) {
    float acc = bd1[j];
#pragma unroll
    for (int k = 0; k < H; ++k) acc = fmaf(s_h[k], Wd1[k * 20 + j], acc);
    s_a[j] = fmaxf(acc, 0.f);
  }
  __syncthreads();
  if (j < 20) {
    float acc = bd2[j];
#pragma unroll
    for (int k = 0; k < 20; ++k) acc = fmaf(s_a[k], Wd2[k * 20 + j], acc);
    s_b[j] = fmaxf(acc, 0.f);
  }
  __syncthreads();
  if (j < 10) {
    float acc = bl[j];
#pragma unroll
    for (int k = 0; k < 20; ++k) acc = fmaf(s_b[k], Wl[k * 10 + j], acc);
    out[j] = acc;
  }
}

extern "C" void kernel_launch(void* const* d_in, const int* in_sizes, int n_in,
                              void* d_out, int out_size, void* d_ws, size_t ws_size,
                              hipStream_t stream) {
  const float* x   = (const float*)d_in[0];
  const float* W1  = (const float*)d_in[1];
  const float* U1  = (const float*)d_in[2];
  const float* b1  = (const float*)d_in[3];
  const float* W2  = (const float*)d_in[4];
  const float* U2  = (const float*)d_in[5];
  const float* b2  = (const float*)d_in[6];
  const float* W3  = (const float*)d_in[7];
  const float* U3  = (const float*)d_in[8];
  const float* b3  = (const float*)d_in[9];
  const float* Wd1 = (const float*)d_in[10];
  const float* bd1 = (const float*)d_in[11];
  const float* Wd2 = (const float*)d_in[12];
  const float* bd2 = (const float*)d_in[13];
  const float* Wl  = (const float*)d_in[14];
  const float* bl  = (const float*)d_in[15];
  const int T = in_sizes[0] / 2;  // 16384

  // workspace: xw [T,256] | h3 [64]
  float* xw = (float*)d_ws;
  float* h3 = xw + (size_t)T * G4;

  proj_x<<<T, G4, 0, stream>>>(x, W1, b1, xw);
  fused_scan<<<1, 768, 0, stream>>>(xw, U1, W2, U2, b2, W3, U3, b3, h3, T);
  head_k<<<1, 64, 0, stream>>>(h3, Wd1, bd1, Wd2, bd2, Wl, bl, (float*)d_out);
}

// Round 10
// 14673.579 us; speedup vs baseline: 1.9349x; 1.2828x over previous
//
#include <hip/hip_runtime.h>

#define H 64
#define G4 256  // 4*H

// __builtin_amdgcn_cvt_pkrtz returns a __fp16 vector; __builtin_amdgcn_fdot2
// takes _Float16 vectors. Keep both typedefs and pun through int.
typedef _Float16 f16x2 __attribute__((ext_vector_type(2)));
typedef __fp16 p16x2 __attribute__((ext_vector_type(2)));

__device__ __forceinline__ float sigmoid_f(float x) {
  return 1.f / (1.f + __expf(-x));
}
__device__ __forceinline__ float tanh_f(float x) {
  float e = __expf(2.f * x);
  return 1.f - 2.f / (e + 1.f);
}
__device__ __forceinline__ f16x2 as_h2(int v) {
  union { int i; f16x2 h; } u; u.i = v; return u.h;
}
__device__ __forceinline__ int pack_f16(float lo, float hi) {
  union { p16x2 h; int i; } u;
  u.h = __builtin_amdgcn_cvt_pkrtz(lo, hi);
  return u.i;
}
// Workgroup barrier draining ONLY lgkmcnt (LDS); globals stay in flight.
__device__ __forceinline__ void wg_barrier() {
  asm volatile("s_waitcnt lgkmcnt(0)\n\ts_barrier" ::: "memory");
}

// xw[t][j] = x[t][0]*W[0][j] + x[t][1]*W[1][j] + b[j]   (f32)
__global__ __launch_bounds__(G4) void proj_x(const float* __restrict__ x,
                                             const float* __restrict__ W,
                                             const float* __restrict__ b,
                                             float* __restrict__ xw) {
  const int t = blockIdx.x;
  const int j = threadIdx.x;
  xw[(size_t)t * G4 + j] =
      fmaf(x[2 * t], W[j], fmaf(x[2 * t + 1], W[G4 + j], b[j]));
}

// Fused 3-layer systolic LSTM scan, ONE block, 768 threads = 3 layers x 4
// waves. Thread (L, g, l). Layer L handles t = s - L at global step s.
//
// vs round 9 (readlane version): h is handed off as 32 packed-f16 pairs in
// LDS (sh_h16[L]) and broadcast-read via uniform-address ds_read_b128 —
// 8 reads + 32 fdot2 per 64x64 matrix (0.31 instr/MAC) instead of
// 32 v_readlane + 32 fdot2 (1.0 instr/MAC + SGPR wait-state hazards).
// Cell update runs in ONE designated wave per layer (g == L, which lands on
// SIMD L: one cell wave per SIMD 0..2), not redundantly in all 12 waves.
//
// Sync (2 lgkm-only barriers/step, audit):
//   sh_a:   D writes (pre-B1) / C reads (post-B1)  -> B1
//           C reads (s) / D writes (s+1)           -> B2
//   sh_h16: C writes (post-B1) / D reads (s+1)     -> B2
//           D reads (pre-B1, own + next layer's prev) / C writes (post-B1) -> B1
//   => no parity buffers needed (same discipline as the round-9-proven code).
__global__ __attribute__((amdgpu_flat_work_group_size(768, 768),
                          amdgpu_waves_per_eu(3, 3)))
void fused_scan(const float* __restrict__ xw,  // [T,256] = x@W1+b1 (f32)
                const float* __restrict__ U1,
                const float* __restrict__ W2, const float* __restrict__ U2,
                const float* __restrict__ b2,
                const float* __restrict__ W3, const float* __restrict__ U3,
                const float* __restrict__ b3,
                float* __restrict__ h3out, int T) {
  __shared__ float sh_a[3 * G4];   // gate activations per layer
  __shared__ int4 sh_h16v[3 * 8];  // packed f16 h pairs, per layer (16B-align)
  int* sh_h16 = (int*)sh_h16v;

  const int tid = (int)threadIdx.x;
  const int L = tid >> 8;   // layer (wave-uniform)
  const int j = tid & 255;  // gate column within layer
  const int g = j >> 6;     // gate: 0=i,1=f,2=g(tanh),3=o (wave-uniform)
  const int l = j & 63;     // hidden unit = lane

  const float* U  = (L == 0) ? U1 : ((L == 1) ? U2 : U3);
  const float* Wp = (L == 0) ? U1 : ((L == 1) ? W2 : W3);  // dummy for L0

  // f16-packed weight columns: upk[k] = (U[2k][j], U[2k+1][j])
  int upk[32], wpk[32];
#pragma unroll
  for (int k = 0; k < 32; ++k)
    upk[k] = pack_f16(U[(2 * k) * G4 + j], U[(2 * k + 1) * G4 + j]);
#pragma unroll
  for (int k = 0; k < 32; ++k)
    wpk[k] = pack_f16(Wp[(2 * k) * G4 + j], Wp[(2 * k + 1) * G4 + j]);
#pragma unroll
  for (int k = 0; k < 32; ++k) asm volatile("" : "+v"(upk[k]));
#pragma unroll
  for (int k = 0; k < 32; ++k) asm volatile("" : "+v"(wpk[k]));

  float bj = 0.f;
  if (L == 1) bj = b2[j];
  if (L == 2) bj = b3[j];

  const bool is_cell = (g == L);  // designated cell wave (SIMD L)
  float c = 0.f;

  if (tid < 96) ((int*)sh_h16)[tid] = 0;
  wg_barrier();

  float nxt = 0.f;
  if (L == 0) nxt = xw[j];  // 1-step-ahead xw prefetch

  const int S = T + 2;
  for (int s = 0; s < S; ++s) {
    const int t = s - L;
    const bool active = (t >= 0) && (t < T);  // uniform within layer

    // ---- phase D: dot + activation ----
    if (active) {
      float z0, z1 = 0.f;
      if (L == 0) {
        z0 = nxt;
        const int sn = (s + 1 < T) ? (s + 1) : (T - 1);
        nxt = xw[(size_t)sn * G4 + j];  // fire-and-forget prefetch
      } else {
        z0 = bj;
      }
      const int4* hb = &sh_h16v[L * 8];  // own h, uniform addr (broadcast)
#pragma unroll
      for (int r = 0; r < 8; ++r) {
        const int4 hv = hb[r];
        z0 = __builtin_amdgcn_fdot2(as_h2(hv.x), as_h2(upk[4 * r]), z0, false);
        z1 = __builtin_amdgcn_fdot2(as_h2(hv.y), as_h2(upk[4 * r + 1]), z1,
                                    false);
        z0 = __builtin_amdgcn_fdot2(as_h2(hv.z), as_h2(upk[4 * r + 2]), z0,
                                    false);
        z1 = __builtin_amdgcn_fdot2(as_h2(hv.w), as_h2(upk[4 * r + 3]), z1,
                                    false);
      }
      if (L > 0) {
        float z2 = 0.f, z3 = 0.f;
        const int4* pb = &sh_h16v[(L - 1) * 8];  // prev-layer h
#pragma unroll
        for (int r = 0; r < 8; ++r) {
          const int4 hv = pb[r];
          z2 = __builtin_amdgcn_fdot2(as_h2(hv.x), as_h2(wpk[4 * r]), z2,
                                      false);
          z3 = __builtin_amdgcn_fdot2(as_h2(hv.y), as_h2(wpk[4 * r + 1]), z3,
                                      false);
          z2 = __builtin_amdgcn_fdot2(as_h2(hv.z), as_h2(wpk[4 * r + 2]), z2,
                                      false);
          z3 = __builtin_amdgcn_fdot2(as_h2(hv.w), as_h2(wpk[4 * r + 3]), z3,
                                      false);
        }
        z0 += z2 + z3;
      }
      const float z = z0 + z1;
      sh_a[(L << 8) + j] = (g == 2) ? tanh_f(z) : sigmoid_f(z);
    }
    wg_barrier();  // B1

    // ---- phase C: designated wave only (one per SIMD 0..2) ----
    if (active && is_cell) {
      const int base = (L << 8) + l;
      const float gi = sh_a[base];
      const float gf = sh_a[base + 64];
      const float gg = sh_a[base + 128];
      const float go = sh_a[base + 192];
      c = fmaf(gf, c, gi * gg);
      const float h = go * tanh_f(c);
      const float hx = __shfl_xor(h, 1, 64);
      const int pair = pack_f16(h, hx);  // even lane 2k: (h[2k], h[2k+1])
      if ((l & 1) == 0) sh_h16[(L << 5) + (l >> 1)] = pair;
      if (L == 2 && t == T - 1) h3out[l] = h;  // f32 result for the head
    }
    wg_barrier();  // B2
  }
}

// Dense head: relu(h3@Wd1+bd1) -> relu(@Wd2+bd2) -> @Wl+bl  (all f32)
__global__ __launch_bounds__(64) void head_k(const float* __restrict__ hlast,
                                             const float* __restrict__ Wd1,
                                             const float* __restrict__ bd1,
                                             const float* __restrict__ Wd2,
                                             const float* __restrict__ bd2,
                                             const float* __restrict__ Wl,
                                             const float* __restrict__ bl,
                                             float* __restrict__ out) {
  __shared__ float s_h[H];
  __shared__ float s_a[20];
  __shared__ float s_b[20];
  const int j = threadIdx.x;
  s_h[j] = hlast[j];
  __syncthreads();
  if (j < 20) {
    float acc = bd1[j];
#pragma unroll
    for (int k = 0; k < H; ++k) acc = fmaf(s_h[k], Wd1[k * 20 + j], acc);
    s_a[j] = fmaxf(acc, 0.f);
  }
  __syncthreads();
  if (j < 20) {
    float acc = bd2[j];
#pragma unroll
    for (int k = 0; k < 20; ++k) acc = fmaf(s_a[k], Wd2[k * 20 + j], acc);
    s_b[j] = fmaxf(acc, 0.f);
  }
  __syncthreads();
  if (j < 10) {
    float acc = bl[j];
#pragma unroll
    for (int k = 0; k < 20; ++k) acc = fmaf(s_b[k], Wl[k * 10 + j], acc);
    out[j] = acc;
  }
}

extern "C" void kernel_launch(void* const* d_in, const int* in_sizes, int n_in,
                              void* d_out, int out_size, void* d_ws, size_t ws_size,
                              hipStream_t stream) {
  const float* x   = (const float*)d_in[0];
  const float* W1  = (const float*)d_in[1];
  const float* U1  = (const float*)d_in[2];
  const float* b1  = (const float*)d_in[3];
  const float* W2  = (const float*)d_in[4];
  const float* U2  = (const float*)d_in[5];
  const float* b2  = (const float*)d_in[6];
  const float* W3  = (const float*)d_in[7];
  const float* U3  = (const float*)d_in[8];
  const float* b3  = (const float*)d_in[9];
  const float* Wd1 = (const float*)d_in[10];
  const float* bd1 = (const float*)d_in[11];
  const float* Wd2 = (const float*)d_in[12];
  const float* bd2 = (const float*)d_in[13];
  const float* Wl  = (const float*)d_in[14];
  const float* bl  = (const float*)d_in[15];
  const int T = in_sizes[0] / 2;  // 16384

  // workspace: xw [T,256] | h3 [64]
  float* xw = (float*)d_ws;
  float* h3 = xw + (size_t)T * G4;

  proj_x<<<T, G4, 0, stream>>>(x, W1, b1, xw);
  fused_scan<<<1, 768, 0, stream>>>(xw, U1, W2, U2, b2, W3, U3, b3, h3, T);
  head_k<<<1, 64, 0, stream>>>(h3, Wd1, bd1, Wd2, bd2, Wl, bl, (float*)d_out);
}